// Round 16
// baseline (43.311 us; speedup 1.0000x reference)
//
#include <hip/hip_runtime.h>
#include <stdint.h>

#define BATCH 128
#define MAXN 1024
#define NF 9
#define DIM 256
#define NCLS 10
#define NP 174          // per-field projected P rows

// 3-table combined layout (rows of 256 bf16):
//  T0: [0,119)      field0
//  T1: [119,839)    fields1-3  idx = (i1*12+i2)*12+i3   (5*12*12=720)
//  T2: [839,2279)   fields4-8  idx = (((i4*6+i5)*6+i6)*2+i7)*2+i8 (1440)
#define T1BASE 119
#define T2BASE 839
#define QROWS 2279

typedef __attribute__((ext_vector_type(4))) float f32x4;

__device__ __forceinline__ ushort f32_to_bf16_rne(float x) {
  uint32_t u = __float_as_uint(x);
  u += 0x7fffu + ((u >> 16) & 1u);
  return (ushort)(u >> 16);
}

__device__ __forceinline__ float bf_lo(uint32_t v) { return __uint_as_float(v << 16); }
__device__ __forceinline__ float bf_hi(uint32_t v) { return __uint_as_float(v & 0xffff0000u); }

// ---------------------------------------------------------------------------
// Prep A: 184 blocks. bid<174: P[r][o] = W1[o]·atom_emb[r]  (f32, 174x256)
//         bid>=174: clsT[c][o] = lin_b[o] + W2[o]·rxn_emb[c]
// (lin_w 512KB is L2-resident across blocks; dot re-reads hit L2.)
// ---------------------------------------------------------------------------
__global__ __launch_bounds__(256) void prepA_kernel(
    const float* __restrict__ rxn_emb, const float* __restrict__ lin_w,
    const float* __restrict__ lin_b, const float* __restrict__ atom_emb,
    float* __restrict__ P, float* __restrict__ clsT)
{
  __shared__ float S[DIM];
  const int bid = blockIdx.x;
  const int t = threadIdx.x;
  const bool isCls = bid >= NP;
  S[t] = isCls ? rxn_emb[(bid - NP) * DIM + t] : atom_emb[bid * DIM + t];
  __syncthreads();
  const float* wrow = lin_w + (size_t)t * 2 * DIM + (isCls ? DIM : 0);
  float acc = isCls ? lin_b[t] : 0.f;
#pragma unroll 4
  for (int d = 0; d < DIM; d += 4) {
    float4 w4 = *(const float4*)(wrow + d);
    acc += w4.x * S[d] + w4.y * S[d + 1] + w4.z * S[d + 2] + w4.w * S[d + 3];
  }
  if (isCls) clsT[(bid - NP) * DIM + t] = acc;
  else       P[bid * DIM + t] = acc;
}

// ---------------------------------------------------------------------------
// Prep B: 2279 blocks; row q = sum of 1/3/5 P rows, rounded ONCE to bf16.
// Per-field P bases: 0,119,124,136,148,158,164,170,172.
// ---------------------------------------------------------------------------
__global__ __launch_bounds__(256) void prepB_kernel(
    const float* __restrict__ P, ushort* __restrict__ Qb)
{
  const int q = blockIdx.x;
  const int t = threadIdx.x;
  float v;
  if (q < T1BASE) {
    v = P[q * DIM + t];
  } else if (q < T2BASE) {
    int x = q - T1BASE;
    int i1 = x / 144, r = x % 144, i2 = r / 12, i3 = r % 12;
    v = P[(119 + i1) * DIM + t] + P[(124 + i2) * DIM + t] + P[(136 + i3) * DIM + t];
  } else {
    int x = q - T2BASE;
    int i8 = x & 1; x >>= 1;
    int i7 = x & 1; x >>= 1;
    int i6 = x % 6; x /= 6;
    int i5 = x % 6, i4 = x / 6;
    v = P[(148 + i4) * DIM + t] + P[(158 + i5) * DIM + t] + P[(164 + i6) * DIM + t]
      + P[(170 + i7) * DIM + t] + P[(172 + i8) * DIM + t];
  }
  Qb[(size_t)q * DIM + t] = f32_to_bf16_rne(v);
}

// ---------------------------------------------------------------------------
// Main: 4096 blocks x 256 thr (XCD-bijective swizzled: 4096 = 8 x 512, each
// XCD owns one contiguous ~17MB output region). Wave = 8 nodes = 4 pairs.
// HALF-WAVE = ONE FULL NODE ROW (32 lanes x 8 cols): hi=0 -> node 2p,
// hi=1 -> node 2p+1; halves independent -> ZERO shuffles. Per pair: 3 paired
// full-wave b128 gathers (each reads two full 512B rows) + 2 b128 stores.
// Per node: 2.5 VMEM (r15: 3), 1.5KB reads (r15: 2KB), 0 DS (r15: 4).
// ---------------------------------------------------------------------------
__global__ __launch_bounds__(256) void main_kernel(
    const int* __restrict__ node_feat, const int* __restrict__ num_nodes,
    const int* __restrict__ rxn_class,
    const ushort* __restrict__ Qb, const float* __restrict__ clsT,
    float* __restrict__ out)
{
  const int tid = threadIdx.x;
  const int lane = tid & 63;
  const int w = __builtin_amdgcn_readfirstlane(tid >> 6);
  const int bid = blockIdx.x;
  const int vbid = (bid & 7) * 512 + (bid >> 3);   // bijective XCD swizzle
  const int wid = vbid * 4 + w;         // 0..16383
  const int b = wid >> 7;               // 128 waves per batch
  const int n0 = (wid & 127) << 3;      // 8 nodes per wave
  const int nn = num_nodes[b];
  const int cls = rxn_class[b];
  const f32x4* __restrict__ clsT4 = (const f32x4*)clsT;
  f32x4* __restrict__ out4 = (f32x4*)out + (size_t)(b * MAXN + n0) * 64;

  if (n0 >= nn) {  // fully masked strip: pure store stream (slot = lane)
    const f32x4 cfL = clsT4[cls * 64 + lane];
#pragma unroll
    for (int i = 0; i < 8; ++i)
      out4[i * 64 + lane] = cfL;
    return;
  }

  const int li = lane & 31;
  const int hi = lane >> 5;             // 0 -> node 2p, 1 -> node 2p+1
  const f32x4 cfA = clsT4[cls * 64 + 2 * li];      // cols [8li, 8li+4)
  const f32x4 cfB = clsT4[cls * 64 + 2 * li + 1];  // cols [8li+4, 8li+8)
  const int* __restrict__ p = node_feat + (size_t)(b * MAXN + n0) * NF;

#define PAIR_BODY(pi, MASKED)                                                  \
  {                                                                            \
    const int* pA = p + (2 * (pi)) * NF;                                       \
    const int* pB = p + (2 * (pi) + 1) * NF;                                   \
    const int jA0 = pA[0];                                                     \
    const int jA1 = T1BASE + (pA[1] * 12 + pA[2]) * 12 + pA[3];                \
    const int jA2 = T2BASE + (((pA[4] * 6 + pA[5]) * 6 + pA[6]) * 2            \
                              + pA[7]) * 2 + pA[8];                            \
    const int jB0 = pB[0];                                                     \
    const int jB1 = T1BASE + (pB[1] * 12 + pB[2]) * 12 + pB[3];                \
    const int jB2 = T2BASE + (((pB[4] * 6 + pB[5]) * 6 + pB[6]) * 2            \
                              + pB[7]) * 2 + pB[8];                            \
    const uint4 g0 = *(const uint4*)(Qb + (size_t)(hi ? jB0 : jA0) * DIM + li * 8); \
    const uint4 g1 = *(const uint4*)(Qb + (size_t)(hi ? jB1 : jA1) * DIM + li * 8); \
    const uint4 g2 = *(const uint4*)(Qb + (size_t)(hi ? jB2 : jA2) * DIM + li * 8); \
    f32x4 lo, hi4;                                                             \
    lo.x = bf_lo(g0.x) + bf_lo(g1.x) + bf_lo(g2.x);                            \
    lo.y = bf_hi(g0.x) + bf_hi(g1.x) + bf_hi(g2.x);                            \
    lo.z = bf_lo(g0.y) + bf_lo(g1.y) + bf_lo(g2.y);                            \
    lo.w = bf_hi(g0.y) + bf_hi(g1.y) + bf_hi(g2.y);                            \
    hi4.x = bf_lo(g0.z) + bf_lo(g1.z) + bf_lo(g2.z);                           \
    hi4.y = bf_hi(g0.z) + bf_hi(g1.z) + bf_hi(g2.z);                           \
    hi4.z = bf_lo(g0.w) + bf_lo(g1.w) + bf_lo(g2.w);                           \
    hi4.w = bf_hi(g0.w) + bf_hi(g1.w) + bf_hi(g2.w);                           \
    const int node = 2 * (pi) + hi;                                            \
    if (MASKED) {                                                              \
      const float m = (n0 + node < nn) ? 1.f : 0.f;                            \
      out4[node * 64 + 2 * li]     = cfA + m * lo;                             \
      out4[node * 64 + 2 * li + 1] = cfB + m * hi4;                            \
    } else {                                                                   \
      out4[node * 64 + 2 * li]     = cfA + lo;                                 \
      out4[node * 64 + 2 * li + 1] = cfB + hi4;                                \
    }                                                                          \
  }

  if (n0 + 8 <= nn) {  // fully valid strip
#pragma unroll
    for (int pi = 0; pi < 4; ++pi)
      PAIR_BODY(pi, 0)
    return;
  }

  // partial strip (<=1 per batch): branchless per-lane mask (gathers always
  // safe — all node_feat slots hold valid categorical indices)
#pragma unroll
  for (int pi = 0; pi < 4; ++pi)
    PAIR_BODY(pi, 1)
#undef PAIR_BODY
}

extern "C" void kernel_launch(void* const* d_in, const int* in_sizes, int n_in,
                              void* d_out, int out_size, void* d_ws, size_t ws_size,
                              hipStream_t stream) {
  const int* node_feat = (const int*)d_in[0];
  const int* num_nodes = (const int*)d_in[1];
  const int* rxn_class = (const int*)d_in[2];
  const float* atom_emb = (const float*)d_in[3];
  const float* rxn_emb = (const float*)d_in[4];
  const float* lin_w = (const float*)d_in[5];
  const float* lin_b = (const float*)d_in[6];
  float* outp = (float*)d_out;

  // workspace: Qb bf16 (2279*256*2 = 1166848 B) | clsT (10240 B) | P (178176 B)
  ushort* Qb = (ushort*)d_ws;
  float* clsT = (float*)((char*)d_ws + 1166848);
  float* P = (float*)((char*)d_ws + 1166848 + 10240);

  prepA_kernel<<<NP + NCLS, 256, 0, stream>>>(rxn_emb, lin_w, lin_b,
                                              atom_emb, P, clsT);
  prepB_kernel<<<QROWS, 256, 0, stream>>>(P, Qb);
  main_kernel<<<4096, 256, 0, stream>>>(node_feat, num_nodes, rxn_class,
                                        Qb, clsT, outp);
}

// Round 17
// 41.164 us; speedup vs baseline: 1.0522x; 1.0522x over previous
//
#include <hip/hip_runtime.h>
#include <stdint.h>

#define BATCH 128
#define MAXN 1024
#define NF 9
#define DIM 256
#define NCLS 10

// Combined-table sections (rows of 256):
#define BASE1 119
#define BASE2 179
#define BASE3 299
#define QROWS 443
#define TBLK 114   // 3 cls blocks + 111 Q blocks

typedef __attribute__((ext_vector_type(4))) float f32x4;

__device__ __forceinline__ ushort f32_to_bf16_rne(float x) {
  uint32_t u = __float_as_uint(x);
  u += 0x7fffu + ((u >> 16) & 1u);
  return (ushort)(u >> 16);
}

// ---------------------------------------------------------------------------
// Prep (r15's proven shape, ~2.5us): 114 blocks, 4 rows/block, one W sweep.
//  bid in [0,3):   clsT[c][o] f32 = lin_b[o] + W2[o]·rxn_emb[c]
//  bid in [3,114): Qb[q][o] bf16 = W1[o]·S_q  (row-major 443x256, 512B rows)
// ---------------------------------------------------------------------------
__global__ __launch_bounds__(256) void prep_kernel(
    const float* __restrict__ rxn_emb, const float* __restrict__ lin_w,
    const float* __restrict__ lin_b, const float* __restrict__ atom_emb,
    ushort* __restrict__ Qb, float* __restrict__ clsT)
{
  __shared__ float S[4][DIM];
  const int bid = blockIdx.x;
  const int t = threadIdx.x;
  const bool isCls = bid < 3;
  const int row0 = isCls ? bid * 4 : (bid - 3) * 4;
  const int rmax = isCls ? NCLS : QROWS;
  const int nrows = (rmax - row0 < 4) ? (rmax - row0) : 4;

#pragma unroll
  for (int r = 0; r < 4; ++r) {
    float v = 0.f;
    if (r < nrows) {
      const int q = row0 + r;
      if (isCls) {
        v = rxn_emb[q * DIM + t];
      } else if (q < BASE1) {
        v = atom_emb[q * DIM + t];
      } else if (q < BASE2) {
        int x = q - BASE1;
        v = atom_emb[(119 + x / 12) * DIM + t] + atom_emb[(124 + x % 12) * DIM + t];
      } else if (q < BASE3) {
        int x = q - BASE2;
        v = atom_emb[(136 + x / 10) * DIM + t] + atom_emb[(148 + x % 10) * DIM + t];
      } else {
        int x = q - BASE3;
        int i8 = x & 1, i7 = (x >> 1) & 1, y = x >> 2;
        v = atom_emb[(158 + y / 6) * DIM + t] + atom_emb[(164 + y % 6) * DIM + t]
          + atom_emb[(170 + i7) * DIM + t] + atom_emb[(172 + i8) * DIM + t];
      }
    }
    S[r][t] = v;
  }
  __syncthreads();

  const float* wrow = lin_w + (size_t)t * 2 * DIM + (isCls ? DIM : 0);
  const float init = isCls ? lin_b[t] : 0.f;
  float a0 = init, a1 = init, a2 = init, a3 = init;
#pragma unroll 4
  for (int d = 0; d < DIM; d += 4) {
    float4 w4 = *(const float4*)(wrow + d);
    a0 += w4.x * S[0][d] + w4.y * S[0][d + 1] + w4.z * S[0][d + 2] + w4.w * S[0][d + 3];
    a1 += w4.x * S[1][d] + w4.y * S[1][d + 1] + w4.z * S[1][d + 2] + w4.w * S[1][d + 3];
    a2 += w4.x * S[2][d] + w4.y * S[2][d + 1] + w4.z * S[2][d + 2] + w4.w * S[2][d + 3];
    a3 += w4.x * S[3][d] + w4.y * S[3][d + 1] + w4.z * S[3][d + 2] + w4.w * S[3][d + 3];
  }
  if (isCls) {
    if (0 < nrows) clsT[(row0 + 0) * DIM + t] = a0;
    if (1 < nrows) clsT[(row0 + 1) * DIM + t] = a1;
    if (2 < nrows) clsT[(row0 + 2) * DIM + t] = a2;
    if (3 < nrows) clsT[(row0 + 3) * DIM + t] = a3;
  } else {
    if (0 < nrows) Qb[(row0 + 0) * DIM + t] = f32_to_bf16_rne(a0);
    if (1 < nrows) Qb[(row0 + 1) * DIM + t] = f32_to_bf16_rne(a1);
    if (2 < nrows) Qb[(row0 + 2) * DIM + t] = f32_to_bf16_rne(a2);
    if (3 < nrows) Qb[(row0 + 3) * DIM + t] = f32_to_bf16_rne(a3);
  }
}

// ---------------------------------------------------------------------------
// Main: r15 skeleton (4096 blocks x 256 thr, wave = 8 nodes, paired wide
// gathers, shfl combine). SINGLE CHANGE: gathers are L1-BYPASS (sc0) via
// inline asm, PHASE-SPLIT per strip:
//   ph0: all index math (compiler-managed idx loads drain here)
//   ph1: 16x global_load_dwordx4 ... sc0 back-to-back (no L1 allocate/MSHR)
//   ph2: s_waitcnt vmcnt(0) + sched_barrier(0)   [rule #18 fence]
//   ph3: unpack + shfl_xor combine + 8 coalesced stores
// Theory: gathers 100%-miss the 32KB L1 (227KB table); per-CU L1 MSHR count
// caps misses at ~0.1/cyc -> ~17us serialization, the unexplained residual
// common to every global-gather variant. sc0 reads L2 directly.
// ---------------------------------------------------------------------------
__global__ __launch_bounds__(256) void main_kernel(
    const int* __restrict__ node_feat, const int* __restrict__ num_nodes,
    const int* __restrict__ rxn_class,
    const ushort* __restrict__ Qb, const float* __restrict__ clsT,
    float* __restrict__ out)
{
  const int tid = threadIdx.x;
  const int lane = tid & 63;
  const int w = __builtin_amdgcn_readfirstlane(tid >> 6);
  const int wid = blockIdx.x * 4 + w;   // 0..16383
  const int b = wid >> 7;               // 128 waves per batch
  const int n0 = (wid & 127) << 3;      // 8 nodes per wave
  const int nn = num_nodes[b];

  const int li = lane & 31;
  const int hi = lane >> 5;             // half-wave id
  const int slot = 2 * li + hi;         // f32x4 slot in the 256-col row

  const f32x4 cf = ((const f32x4*)clsT)[rxn_class[b] * 64 + slot];
  f32x4* __restrict__ outp = (f32x4*)out + ((size_t)(b * MAXN + n0)) * 64 + slot;

  if (n0 >= nn) {  // fully masked strip: pure b128 store stream
#pragma unroll
    for (int i = 0; i < 8; ++i)
      outp[i * 64] = cf;
    return;
  }

  const int* __restrict__ p = node_feat + (size_t)(b * MAXN + n0) * NF;

  if (n0 + 8 <= nn) {  // fully valid strip — phase-split sc0 path
    // ph0: all indices (idx loads + SALU/VALU math; compiler drains them)
    int rAB[8], rCD[8];
#pragma unroll
    for (int i = 0; i < 8; ++i) {
      const int j0 = p[i * NF + 0];
      const int j1 = BASE1 + p[i * NF + 1] * 12 + p[i * NF + 2];
      const int j2 = BASE2 + p[i * NF + 3] * 10 + p[i * NF + 4];
      const int j3 = BASE3 + ((p[i * NF + 5] * 6 + p[i * NF + 6]) * 2
                              + p[i * NF + 7]) * 2 + p[i * NF + 8];
      rAB[i] = hi ? j1 : j0;
      rCD[i] = hi ? j3 : j2;
    }

    // ph1: 16 back-to-back sc0 gathers (bypass L1)
    uint4 g[16];
#pragma unroll
    for (int i = 0; i < 8; ++i) {
      const ushort* aAB = Qb + (size_t)rAB[i] * DIM + li * 8;
      const ushort* aCD = Qb + (size_t)rCD[i] * DIM + li * 8;
      asm volatile("global_load_dwordx4 %0, %1, off sc0"
                   : "=v"(g[2 * i]) : "v"(aAB));
      asm volatile("global_load_dwordx4 %0, %1, off sc0"
                   : "=v"(g[2 * i + 1]) : "v"(aCD));
    }

    // ph2: drain gathers; fence so no consumer is hoisted above (rule #18)
    asm volatile("s_waitcnt vmcnt(0)" ::: "memory");
    __builtin_amdgcn_sched_barrier(0);

    // ph3: unpack + half-wave exchange + stores
#pragma unroll
    for (int i = 0; i < 8; ++i) {
      const uint4 g1 = g[2 * i];
      const uint4 g2 = g[2 * i + 1];
      float pp[8];
      pp[0] = __uint_as_float(g1.x << 16)        + __uint_as_float(g2.x << 16);
      pp[1] = __uint_as_float(g1.x & 0xffff0000u) + __uint_as_float(g2.x & 0xffff0000u);
      pp[2] = __uint_as_float(g1.y << 16)        + __uint_as_float(g2.y << 16);
      pp[3] = __uint_as_float(g1.y & 0xffff0000u) + __uint_as_float(g2.y & 0xffff0000u);
      pp[4] = __uint_as_float(g1.z << 16)        + __uint_as_float(g2.z << 16);
      pp[5] = __uint_as_float(g1.z & 0xffff0000u) + __uint_as_float(g2.z & 0xffff0000u);
      pp[6] = __uint_as_float(g1.w << 16)        + __uint_as_float(g2.w << 16);
      pp[7] = __uint_as_float(g1.w & 0xffff0000u) + __uint_as_float(g2.w & 0xffff0000u);
      f32x4 tot;
#pragma unroll
      for (int k = 0; k < 4; ++k) {
        const float send = hi ? pp[k] : pp[4 + k];
        const float own  = hi ? pp[4 + k] : pp[k];
        const float recv = __shfl_xor(send, 32, 64);
        tot[k] = cf[k] + own + recv;
      }
      outp[i * 64] = tot;
    }
    return;
  }

  // partial strip (<=1 per batch): r15's plain-load branchless-mask path
#pragma unroll 4
  for (int i = 0; i < 8; ++i) {
    const int j0 = p[i * NF + 0];
    const int j1 = BASE1 + p[i * NF + 1] * 12 + p[i * NF + 2];
    const int j2 = BASE2 + p[i * NF + 3] * 10 + p[i * NF + 4];
    const int j3 = BASE3 + ((p[i * NF + 5] * 6 + p[i * NF + 6]) * 2
                            + p[i * NF + 7]) * 2 + p[i * NF + 8];
    const int rAB = hi ? j1 : j0;
    const int rCD = hi ? j3 : j2;
    const uint4 g1 = *(const uint4*)(Qb + (size_t)rAB * DIM + li * 8);
    const uint4 g2 = *(const uint4*)(Qb + (size_t)rCD * DIM + li * 8);
    float pp[8];
    pp[0] = __uint_as_float(g1.x << 16)        + __uint_as_float(g2.x << 16);
    pp[1] = __uint_as_float(g1.x & 0xffff0000u) + __uint_as_float(g2.x & 0xffff0000u);
    pp[2] = __uint_as_float(g1.y << 16)        + __uint_as_float(g2.y << 16);
    pp[3] = __uint_as_float(g1.y & 0xffff0000u) + __uint_as_float(g2.y & 0xffff0000u);
    pp[4] = __uint_as_float(g1.z << 16)        + __uint_as_float(g2.z << 16);
    pp[5] = __uint_as_float(g1.z & 0xffff0000u) + __uint_as_float(g2.z & 0xffff0000u);
    pp[6] = __uint_as_float(g1.w << 16)        + __uint_as_float(g2.w << 16);
    pp[7] = __uint_as_float(g1.w & 0xffff0000u) + __uint_as_float(g2.w & 0xffff0000u);
    const float mval = (n0 + i < nn) ? 1.f : 0.f;
    f32x4 tot;
#pragma unroll
    for (int k = 0; k < 4; ++k) {
      const float send = hi ? pp[k] : pp[4 + k];
      const float own  = hi ? pp[4 + k] : pp[k];
      const float recv = __shfl_xor(send, 32, 64);
      tot[k] = cf[k] + mval * (own + recv);
    }
    outp[i * 64] = tot;
  }
}

extern "C" void kernel_launch(void* const* d_in, const int* in_sizes, int n_in,
                              void* d_out, int out_size, void* d_ws, size_t ws_size,
                              hipStream_t stream) {
  const int* node_feat = (const int*)d_in[0];
  const int* num_nodes = (const int*)d_in[1];
  const int* rxn_class = (const int*)d_in[2];
  const float* atom_emb = (const float*)d_in[3];
  const float* rxn_emb = (const float*)d_in[4];
  const float* lin_w = (const float*)d_in[5];
  const float* lin_b = (const float*)d_in[6];
  float* outp = (float*)d_out;

  // workspace: Qb row-major bf16 (226816 B) | clsT (10240 B)
  ushort* Qb = (ushort*)d_ws;
  float* clsT = (float*)((char*)d_ws + QROWS * DIM * sizeof(ushort));

  prep_kernel<<<TBLK, 256, 0, stream>>>(rxn_emb, lin_w, lin_b, atom_emb,
                                        Qb, clsT);
  main_kernel<<<4096, 256, 0, stream>>>(node_feat, num_nodes, rxn_class,
                                        Qb, clsT, outp);
}

// Round 18
// 40.871 us; speedup vs baseline: 1.0597x; 1.0072x over previous
//
#include <hip/hip_runtime.h>
#include <stdint.h>

#define BATCH 128
#define MAXN 1024
#define NF 9
#define DIM 256
#define NCLS 10

// Combined-table sections (rows of 256):
#define BASE1 119
#define BASE2 179
#define BASE3 299
#define QROWS 443
#define TBLK 114   // 3 cls blocks + 111 Q blocks

typedef __attribute__((ext_vector_type(4))) float f32x4;

__device__ __forceinline__ ushort f32_to_bf16_rne(float x) {
  uint32_t u = __float_as_uint(x);
  u += 0x7fffu + ((u >> 16) & 1u);
  return (ushort)(u >> 16);
}

// ---------------------------------------------------------------------------
// Prep (proven ~2.5us): 114 blocks, 4 table rows/block, one W sweep amortized.
//  bid in [0,3):   clsT[c][o] f32 = lin_b[o] + W2[o]·rxn_emb[c]
//  bid in [3,114): Qb[q][o] bf16 = W1[o]·S_q  (row-major 443x256, 512B rows)
// ---------------------------------------------------------------------------
__global__ __launch_bounds__(256) void prep_kernel(
    const float* __restrict__ rxn_emb, const float* __restrict__ lin_w,
    const float* __restrict__ lin_b, const float* __restrict__ atom_emb,
    ushort* __restrict__ Qb, float* __restrict__ clsT)
{
  __shared__ float S[4][DIM];
  const int bid = blockIdx.x;
  const int t = threadIdx.x;
  const bool isCls = bid < 3;
  const int row0 = isCls ? bid * 4 : (bid - 3) * 4;
  const int rmax = isCls ? NCLS : QROWS;
  const int nrows = (rmax - row0 < 4) ? (rmax - row0) : 4;

#pragma unroll
  for (int r = 0; r < 4; ++r) {
    float v = 0.f;
    if (r < nrows) {
      const int q = row0 + r;
      if (isCls) {
        v = rxn_emb[q * DIM + t];
      } else if (q < BASE1) {
        v = atom_emb[q * DIM + t];
      } else if (q < BASE2) {
        int x = q - BASE1;
        v = atom_emb[(119 + x / 12) * DIM + t] + atom_emb[(124 + x % 12) * DIM + t];
      } else if (q < BASE3) {
        int x = q - BASE2;
        v = atom_emb[(136 + x / 10) * DIM + t] + atom_emb[(148 + x % 10) * DIM + t];
      } else {
        int x = q - BASE3;
        int i8 = x & 1, i7 = (x >> 1) & 1, y = x >> 2;
        v = atom_emb[(158 + y / 6) * DIM + t] + atom_emb[(164 + y % 6) * DIM + t]
          + atom_emb[(170 + i7) * DIM + t] + atom_emb[(172 + i8) * DIM + t];
      }
    }
    S[r][t] = v;
  }
  __syncthreads();

  const float* wrow = lin_w + (size_t)t * 2 * DIM + (isCls ? DIM : 0);
  const float init = isCls ? lin_b[t] : 0.f;
  float a0 = init, a1 = init, a2 = init, a3 = init;
#pragma unroll 4
  for (int d = 0; d < DIM; d += 4) {
    float4 w4 = *(const float4*)(wrow + d);
    a0 += w4.x * S[0][d] + w4.y * S[0][d + 1] + w4.z * S[0][d + 2] + w4.w * S[0][d + 3];
    a1 += w4.x * S[1][d] + w4.y * S[1][d + 1] + w4.z * S[1][d + 2] + w4.w * S[1][d + 3];
    a2 += w4.x * S[2][d] + w4.y * S[2][d + 1] + w4.z * S[2][d + 2] + w4.w * S[2][d + 3];
    a3 += w4.x * S[3][d] + w4.y * S[3][d + 1] + w4.z * S[3][d + 2] + w4.w * S[3][d + 3];
  }
  if (isCls) {
    if (0 < nrows) clsT[(row0 + 0) * DIM + t] = a0;
    if (1 < nrows) clsT[(row0 + 1) * DIM + t] = a1;
    if (2 < nrows) clsT[(row0 + 2) * DIM + t] = a2;
    if (3 < nrows) clsT[(row0 + 3) * DIM + t] = a3;
  } else {
    if (0 < nrows) Qb[(row0 + 0) * DIM + t] = f32_to_bf16_rne(a0);
    if (1 < nrows) Qb[(row0 + 1) * DIM + t] = f32_to_bf16_rne(a1);
    if (2 < nrows) Qb[(row0 + 2) * DIM + t] = f32_to_bf16_rne(a2);
    if (3 < nrows) Qb[(row0 + 3) * DIM + t] = f32_to_bf16_rne(a3);
  }
}

// ---------------------------------------------------------------------------
// Main (r15, session-best 40.854us): 4096 blocks x 256 thr, wave = 8 nodes.
// WIDE PAIRED GATHERS: per node, 2x b128 cached gathers (lanes 0-31 carry
// the full row jA/jC, lanes 32-63 jB/jD — one instr reads two whole 512B
// rows); half-wave partials combined with 4 __shfl_xor(..,32). Per node:
// 3 VMEM, all max-width. Plain stores (nt hurt: r7/r8). Slot=2*li+hi keeps
// the 1KB/wave store fully coalesced. Three wave-uniform paths.
// ---------------------------------------------------------------------------
__global__ __launch_bounds__(256) void main_kernel(
    const int* __restrict__ node_feat, const int* __restrict__ num_nodes,
    const int* __restrict__ rxn_class,
    const ushort* __restrict__ Qb, const float* __restrict__ clsT,
    float* __restrict__ out)
{
  const int tid = threadIdx.x;
  const int lane = tid & 63;
  const int w = __builtin_amdgcn_readfirstlane(tid >> 6);
  const int wid = blockIdx.x * 4 + w;   // 0..16383
  const int b = wid >> 7;               // 128 waves per batch
  const int n0 = (wid & 127) << 3;      // 8 nodes per wave
  const int nn = num_nodes[b];

  const int li = lane & 31;
  const int hi = lane >> 5;             // half-wave id
  const int slot = 2 * li + hi;         // f32x4 slot in the 256-col row

  const f32x4 cf = ((const f32x4*)clsT)[rxn_class[b] * 64 + slot];
  f32x4* __restrict__ outp = (f32x4*)out + ((size_t)(b * MAXN + n0)) * 64 + slot;

  if (n0 >= nn) {  // fully masked strip: pure b128 store stream
#pragma unroll
    for (int i = 0; i < 8; ++i)
      outp[i * 64] = cf;
    return;
  }

  const int* __restrict__ p = node_feat + (size_t)(b * MAXN + n0) * NF;

#define NODE_BODY(i, MASKED)                                                   \
  {                                                                            \
    const int j0 = p[(i) * NF + 0];                                            \
    const int j1 = BASE1 + p[(i) * NF + 1] * 12 + p[(i) * NF + 2];             \
    const int j2 = BASE2 + p[(i) * NF + 3] * 10 + p[(i) * NF + 4];             \
    const int j3 = BASE3 + ((p[(i) * NF + 5] * 6 + p[(i) * NF + 6]) * 2        \
                            + p[(i) * NF + 7]) * 2 + p[(i) * NF + 8];          \
    const int rAB = hi ? j1 : j0;                                              \
    const int rCD = hi ? j3 : j2;                                              \
    const uint4 g1 = *(const uint4*)(Qb + rAB * 256 + li * 8);                 \
    const uint4 g2 = *(const uint4*)(Qb + rCD * 256 + li * 8);                 \
    float pp[8];                                                               \
    pp[0] = __uint_as_float(g1.x << 16) + __uint_as_float(g2.x << 16);         \
    pp[1] = __uint_as_float(g1.x & 0xffff0000u) + __uint_as_float(g2.x & 0xffff0000u); \
    pp[2] = __uint_as_float(g1.y << 16) + __uint_as_float(g2.y << 16);         \
    pp[3] = __uint_as_float(g1.y & 0xffff0000u) + __uint_as_float(g2.y & 0xffff0000u); \
    pp[4] = __uint_as_float(g1.z << 16) + __uint_as_float(g2.z << 16);         \
    pp[5] = __uint_as_float(g1.z & 0xffff0000u) + __uint_as_float(g2.z & 0xffff0000u); \
    pp[6] = __uint_as_float(g1.w << 16) + __uint_as_float(g2.w << 16);         \
    pp[7] = __uint_as_float(g1.w & 0xffff0000u) + __uint_as_float(g2.w & 0xffff0000u); \
    f32x4 tot;                                                                 \
    _Pragma("unroll")                                                          \
    for (int k = 0; k < 4; ++k) {                                              \
      const float send = hi ? pp[k] : pp[4 + k];   /* what partner needs */    \
      const float own  = hi ? pp[4 + k] : pp[k];   /* my stored half */        \
      const float recv = __shfl_xor(send, 32, 64);                             \
      tot[k] = MASKED ? (cf[k] + mval * (own + recv)) : (cf[k] + own + recv);  \
    }                                                                          \
    outp[(i) * 64] = tot;                                                      \
  }

  if (n0 + 8 <= nn) {  // fully valid strip
    const float mval = 1.f; (void)mval;
#pragma unroll 4
    for (int i = 0; i < 8; ++i)
      NODE_BODY(i, 0)
    return;
  }

  // partial strip (<=1 per batch): branchless float-mask (gathers always
  // safe — all node_feat slots hold valid categorical indices)
#pragma unroll 4
  for (int i = 0; i < 8; ++i) {
    const float mval = (n0 + i < nn) ? 1.f : 0.f;
    NODE_BODY(i, 1)
  }
#undef NODE_BODY
}

extern "C" void kernel_launch(void* const* d_in, const int* in_sizes, int n_in,
                              void* d_out, int out_size, void* d_ws, size_t ws_size,
                              hipStream_t stream) {
  const int* node_feat = (const int*)d_in[0];
  const int* num_nodes = (const int*)d_in[1];
  const int* rxn_class = (const int*)d_in[2];
  const float* atom_emb = (const float*)d_in[3];
  const float* rxn_emb = (const float*)d_in[4];
  const float* lin_w = (const float*)d_in[5];
  const float* lin_b = (const float*)d_in[6];
  float* outp = (float*)d_out;

  // workspace: Qb row-major bf16 (226816 B) | clsT (10240 B)
  ushort* Qb = (ushort*)d_ws;
  float* clsT = (float*)((char*)d_ws + QROWS * DIM * sizeof(ushort));

  prep_kernel<<<TBLK, 256, 0, stream>>>(rxn_emb, lin_w, lin_b, atom_emb,
                                        Qb, clsT);
  main_kernel<<<4096, 256, 0, stream>>>(node_feat, num_nodes, rxn_class,
                                        Qb, clsT, outp);
}